// Round 4
// baseline (394.788 us; speedup 1.0000x reference)
//
#include <hip/hip_runtime.h>

// VQ nearest-embedding, fused split-bf16 MFMA (4 cross terms, validated numerics).
// argmin_k ||x-e_k||^2 == argmin_k (0.5*||e_k||^2 - x.e_k).
// R4: 512 blocks x 256 thr (4 waves), 3 blocks/CU -> overlapped barrier groups.

typedef __attribute__((ext_vector_type(8))) short short8v;   // 8 bf16 = 4 VGPRs
typedef __attribute__((ext_vector_type(16))) float floatx16; // 32x32 acc
typedef unsigned int uint;
typedef unsigned short ushort;

#define DD 256
#define KK 2048
#define SS 1024
#define NN 32768
#define MT 64       // latents per block
#define NTT 256     // codes per kt tile (8 tiles cover K=2048)
#define LDA 24      // LDS row stride in bf16 elems (48 B: 16B-aligned)
#define MFMA_BF16 __builtin_amdgcn_mfma_f32_32x32x16_bf16

__device__ __forceinline__ ushort f2bf(float f) {   // fp32 -> bf16 RNE
    uint b = __float_as_uint(f);
    return (ushort)((b + 0x7FFFu + ((b >> 16) & 1u)) >> 16);
}

__global__ __launch_bounds__(256) void hn_kernel(const float* __restrict__ emb,
                                                 float* __restrict__ hn) {
    int k = blockIdx.x * 256 + threadIdx.x;
    float a = 0.f;
#pragma unroll 32
    for (int d = 0; d < DD; ++d) { float e = emb[d * KK + k]; a += e * e; }
    hn[k] = 0.5f * a;
}

__global__ __launch_bounds__(256, 3) void vq_fused(
        const float* __restrict__ x, const float* __restrict__ emb,
        const float* __restrict__ hn, float* __restrict__ out) {
    __shared__ ushort Ah[MT * LDA], Al[MT * LDA];       // 3 KB each
    __shared__ ushort Bh[NTT * LDA], Bl[NTT * LDA];     // 12 KB each
    __shared__ float sv[4][8][MT];                      // 8 KB  (wave, kt, row)
    __shared__ int   sc[4][8][MT];                      // 8 KB
    __shared__ int   bc[MT];

    const int tid = threadIdx.x;
    const int lane = tid & 63;
    const int wid = tid >> 6;          // 4 waves, n-split
    const int colk = lane & 31;
    const int half = lane >> 5;
    const int wn = wid * 64;           // wave covers codes [wn, wn+64) of kt tile

    const int base_n = blockIdx.x * MT;
    const int bq = base_n >> 10;          // batch (SS = 1024)
    const int sb = base_n & (SS - 1);     // spatial base

    // staging assignment
    const int row_a = tid & 63;           // A: one latent, 4 d's
    const int dqa = (tid >> 6) * 4;
    const int row_b = tid;                // B: one code, 16 d's

    const float* xb = x + ((size_t)bq * DD + dqa) * SS + sb + row_a;

    floatx16 acc[2][2];
#pragma unroll
    for (int i = 0; i < 2; ++i)
#pragma unroll
        for (int j = 0; j < 2; ++j) acc[i][j] = (floatx16)(0.0f);

    // prefetch chunk 0 (kt=0, dt=0)
    float fa[4], fb[16];
#pragma unroll
    for (int i = 0; i < 4; ++i) fa[i] = xb[(size_t)i * SS];
    {
        const float* p = emb + row_b;
#pragma unroll
        for (int i = 0; i < 16; ++i) fb[i] = p[(size_t)i * KK];
    }

    for (int c = 0; c < 128; ++c) {          // 8 kt x 16 dt chunks of K-depth 16
        const int kt = c >> 4;
        if (c) __syncthreads();              // prev chunk's LDS readers done
        // ---- convert prefetched fa/fb -> split bf16, write LDS ----
        {
            ushort h[4], l[4];
#pragma unroll
            for (int i = 0; i < 4; ++i) {
                h[i] = f2bf(fa[i]);
                float r = fa[i] - __uint_as_float((uint)h[i] << 16);
                l[i] = f2bf(r);
            }
            uint2 hw, lw;
            hw.x = (uint)h[0] | ((uint)h[1] << 16);
            hw.y = (uint)h[2] | ((uint)h[3] << 16);
            lw.x = (uint)l[0] | ((uint)l[1] << 16);
            lw.y = (uint)l[2] | ((uint)l[3] << 16);
            *reinterpret_cast<uint2*>(&Ah[row_a * LDA + dqa]) = hw;
            *reinterpret_cast<uint2*>(&Al[row_a * LDA + dqa]) = lw;

            ushort g[16], m[16];
#pragma unroll
            for (int i = 0; i < 16; ++i) {
                g[i] = f2bf(fb[i]);
                float r = fb[i] - __uint_as_float((uint)g[i] << 16);
                m[i] = f2bf(r);
            }
            uint4 t;
            t.x = (uint)g[0] | ((uint)g[1] << 16);
            t.y = (uint)g[2] | ((uint)g[3] << 16);
            t.z = (uint)g[4] | ((uint)g[5] << 16);
            t.w = (uint)g[6] | ((uint)g[7] << 16);
            *reinterpret_cast<uint4*>(&Bh[row_b * LDA]) = t;
            t.x = (uint)g[8] | ((uint)g[9] << 16);
            t.y = (uint)g[10] | ((uint)g[11] << 16);
            t.z = (uint)g[12] | ((uint)g[13] << 16);
            t.w = (uint)g[14] | ((uint)g[15] << 16);
            *reinterpret_cast<uint4*>(&Bh[row_b * LDA + 8]) = t;
            t.x = (uint)m[0] | ((uint)m[1] << 16);
            t.y = (uint)m[2] | ((uint)m[3] << 16);
            t.z = (uint)m[4] | ((uint)m[5] << 16);
            t.w = (uint)m[6] | ((uint)m[7] << 16);
            *reinterpret_cast<uint4*>(&Bl[row_b * LDA]) = t;
            t.x = (uint)m[8] | ((uint)m[9] << 16);
            t.y = (uint)m[10] | ((uint)m[11] << 16);
            t.z = (uint)m[12] | ((uint)m[13] << 16);
            t.w = (uint)m[14] | ((uint)m[15] << 16);
            *reinterpret_cast<uint4*>(&Bl[row_b * LDA + 8]) = t;
        }
        __syncthreads();
        // ---- prefetch next chunk's globals (in flight during MFMA) ----
        if (c < 127) {
            const int c1 = c + 1;
            const int kt1 = c1 >> 4;
            const int dt1 = (c1 & 15) * 16;
#pragma unroll
            for (int i = 0; i < 4; ++i) fa[i] = xb[(size_t)(dt1 + i) * SS];
            const float* p = emb + (size_t)dt1 * KK + kt1 * NTT + row_b;
#pragma unroll
            for (int i = 0; i < 16; ++i) fb[i] = p[(size_t)i * KK];
        }
        // ---- fragments + 16 MFMA (4 split terms x 2m x 2n tiles) ----
        const int fo = colk * LDA + half * 8;
        short8v ah0 = *reinterpret_cast<const short8v*>(&Ah[fo]);
        short8v ah1 = *reinterpret_cast<const short8v*>(&Ah[fo + 32 * LDA]);
        short8v al0 = *reinterpret_cast<const short8v*>(&Al[fo]);
        short8v al1 = *reinterpret_cast<const short8v*>(&Al[fo + 32 * LDA]);
        short8v bh0 = *reinterpret_cast<const short8v*>(&Bh[fo + wn * LDA]);
        short8v bh1 = *reinterpret_cast<const short8v*>(&Bh[fo + (wn + 32) * LDA]);
        short8v bl0 = *reinterpret_cast<const short8v*>(&Bl[fo + wn * LDA]);
        short8v bl1 = *reinterpret_cast<const short8v*>(&Bl[fo + (wn + 32) * LDA]);

        acc[0][0] = MFMA_BF16(ah0, bh0, acc[0][0], 0, 0, 0);
        acc[0][0] = MFMA_BF16(ah0, bl0, acc[0][0], 0, 0, 0);
        acc[0][0] = MFMA_BF16(al0, bh0, acc[0][0], 0, 0, 0);
        acc[0][0] = MFMA_BF16(al0, bl0, acc[0][0], 0, 0, 0);

        acc[0][1] = MFMA_BF16(ah0, bh1, acc[0][1], 0, 0, 0);
        acc[0][1] = MFMA_BF16(ah0, bl1, acc[0][1], 0, 0, 0);
        acc[0][1] = MFMA_BF16(al0, bh1, acc[0][1], 0, 0, 0);
        acc[0][1] = MFMA_BF16(al0, bl1, acc[0][1], 0, 0, 0);

        acc[1][0] = MFMA_BF16(ah1, bh0, acc[1][0], 0, 0, 0);
        acc[1][0] = MFMA_BF16(ah1, bl0, acc[1][0], 0, 0, 0);
        acc[1][0] = MFMA_BF16(al1, bh0, acc[1][0], 0, 0, 0);
        acc[1][0] = MFMA_BF16(al1, bl0, acc[1][0], 0, 0, 0);

        acc[1][1] = MFMA_BF16(ah1, bh1, acc[1][1], 0, 0, 0);
        acc[1][1] = MFMA_BF16(ah1, bl1, acc[1][1], 0, 0, 0);
        acc[1][1] = MFMA_BF16(al1, bh1, acc[1][1], 0, 0, 0);
        acc[1][1] = MFMA_BF16(al1, bl1, acc[1][1], 0, 0, 0);

        // ---- per-kt epilogue: scores -> butterfly argmin -> LDS, reset acc ----
        if ((c & 15) == 15) {
            const int cd0 = kt * NTT + wn + colk;
            const int cd1 = cd0 + 32;
            const float h0 = hn[cd0];
            const float h1 = hn[cd1];
#pragma unroll
            for (int tm = 0; tm < 2; ++tm) {
#pragma unroll
                for (int r = 0; r < 16; ++r) {
                    float s0 = h0 - acc[tm][0][r];
                    float s1 = h1 - acc[tm][1][r];
                    float v = s0; int cd = cd0;
                    if (s1 < s0) { v = s1; cd = cd1; }   // strict <: smaller code wins ties
#pragma unroll
                    for (int mk = 1; mk < 32; mk <<= 1) {
                        float ov = __shfl_xor(v, mk);
                        int oc = __shfl_xor(cd, mk);
                        if (ov < v || (ov == v && oc < cd)) { v = ov; cd = oc; }
                    }
                    if (colk == 0) {
                        const int row = (r & 3) + 8 * (r >> 2) + 4 * half;  // verified C/D map
                        sv[wid][kt][tm * 32 + row] = v;
                        sc[wid][kt][tm * 32 + row] = cd;
                    }
                    acc[tm][0][r] = 0.f;
                    acc[tm][1][r] = 0.f;
                }
            }
        }
    }

    __syncthreads();
    // ---- combine 4 waves x 8 kt per latent ----
    if (tid < MT) {
        float v = sv[0][0][tid]; int cd = sc[0][0][tid];
#pragma unroll
        for (int g = 0; g < 4; ++g)
#pragma unroll
            for (int t = 0; t < 8; ++t) {
                if (g == 0 && t == 0) continue;
                float ov = sv[g][t][tid]; int oc = sc[g][t][tid];
                if (ov < v || (ov == v && oc < cd)) { v = ov; cd = oc; }
            }
        bc[tid] = cd;
    }
    __syncthreads();
    // ---- fused gather: out[(bq*DD+d)*SS + sb + m] = emb[d*KK + bc[m]] ----
    {
        const int mq = tid & 15;     // float4 group along m (64 latents = 16 groups)
        const int dg = tid >> 4;     // 0..15, 16 d's each
        const int k0 = bc[mq * 4 + 0];
        const int k1 = bc[mq * 4 + 1];
        const int k2 = bc[mq * 4 + 2];
        const int k3 = bc[mq * 4 + 3];
#pragma unroll 4
        for (int dd = 0; dd < 16; ++dd) {
            const int d = dg * 16 + dd;
            const float* er = emb + (size_t)d * KK;
            float4 o = make_float4(er[k0], er[k1], er[k2], er[k3]);
            reinterpret_cast<float4*>(&out[((size_t)bq * DD + d) * SS + sb])[mq] = o;
        }
    }
}

extern "C" void kernel_launch(void* const* d_in, const int* in_sizes, int n_in,
                              void* d_out, int out_size, void* d_ws, size_t ws_size,
                              hipStream_t stream) {
    const float* x = (const float*)d_in[0];     // (32,256,32,32)
    const float* emb = (const float*)d_in[1];   // (256,2048)
    float* out = (float*)d_out;
    float* hn = (float*)d_ws;                   // 2048 f32 = 8 KB (proven safe)

    hipLaunchKernelGGL(hn_kernel, dim3(KK / 256), dim3(256), 0, stream, emb, hn);
    hipLaunchKernelGGL(vq_fused, dim3(NN / MT), dim3(256), 0, stream,
                       x, emb, hn, out);
}

// Round 5
// 269.326 us; speedup vs baseline: 1.4658x; 1.4658x over previous
//
#include <hip/hip_runtime.h>

// VQ nearest-embedding, fused split-fp16 MFMA, double-buffered LDS.
// argmin_k ||x-e_k||^2 == argmin_k (0.5*||e_k||^2 - x.e_k).
// x = xh+xl, e = eh+el (fp16 RNE splits); 3 MFMA terms (hh, hl, lh);
// dropped ll term ~2^-22 relative -> dot error ~1e-5 (same class as the
// validated bf16 4-term from rounds 2-4, which passed with absmax 0).
// R5: MT=128 economics + 1 barrier/chunk via LDS double buffer.

typedef __attribute__((ext_vector_type(8))) _Float16 half8v;  // 8 fp16 = 4 VGPRs
typedef __attribute__((ext_vector_type(16))) float floatx16;  // 32x32 acc
typedef unsigned int uint;
typedef unsigned short ushort;

#define DD 256
#define KK 2048
#define SS 1024
#define NN 32768
#define MT 128      // latents per block
#define NTT 256     // codes per kt tile (8 tiles cover K=2048)
#define LDA 24      // LDS row stride in fp16 elems (48 B: 16B-aligned, banks spread)
#define MFMA_F16 __builtin_amdgcn_mfma_f32_32x32x16_f16

union HU { _Float16 f; ushort u; };

__device__ __forceinline__ void split16(float v, ushort& h, ushort& l) {
    HU a, b;
    a.f = (_Float16)v;                       // RNE
    b.f = (_Float16)(v - (float)a.f);
    h = a.u; l = b.u;
}

__global__ __launch_bounds__(256) void hn_kernel(const float* __restrict__ emb,
                                                 float* __restrict__ hn) {
    int k = blockIdx.x * 256 + threadIdx.x;
    float a = 0.f;
#pragma unroll 32
    for (int d = 0; d < DD; ++d) { float e = emb[d * KK + k]; a += e * e; }
    hn[k] = 0.5f * a;
}

__global__ __launch_bounds__(512, 1) void vq_fused(
        const float* __restrict__ x, const float* __restrict__ emb,
        const float* __restrict__ hn, float* __restrict__ out) {
    __shared__ ushort Ah[2][MT * LDA], Al[2][MT * LDA];     // 6 KB each plane/buf
    __shared__ ushort Bh[2][NTT * LDA], Bl[2][NTT * LDA];   // 12 KB each plane/buf
    __shared__ float sv[4][MT];
    __shared__ int   sc[4][MT];
    __shared__ int   bc[MT];

    const int tid = threadIdx.x;
    const int lane = tid & 63;
    const int wid = tid >> 6;          // 8 waves: 2(m) x 4(n)
    const int colk = lane & 31;
    const int half = lane >> 5;
    const int wm = (wid & 1) * 64;
    const int wn = (wid >> 1) * 64;

    const int base_n = blockIdx.x * MT;
    const int bq = base_n >> 10;          // batch (SS = 1024)
    const int sb = base_n & (SS - 1);     // spatial base

    // staging assignment (512 threads)
    const int lat_a = tid & 127;          // A: one latent, 4 d's
    const int dqa = (tid >> 7) * 4;
    const int cod_b = tid & 255;          // B: one code, 8 d's
    const int dqb = (tid >> 8) * 8;

    const float* xb = x + ((size_t)bq * DD + dqa) * SS + sb + lat_a;

    floatx16 acc[2][2];
#pragma unroll
    for (int i = 0; i < 2; ++i)
#pragma unroll
        for (int j = 0; j < 2; ++j) acc[i][j] = (floatx16)(0.0f);

    float bestv[2][16];
    int bestc[2][16];
#pragma unroll
    for (int t = 0; t < 2; ++t)
#pragma unroll
        for (int r = 0; r < 16; ++r) { bestv[t][r] = 3.4e38f; bestc[t][r] = 0; }

    float fa[4], fb[8];
    // prefetch chunk 0 (kt=0, dt=0)
#pragma unroll
    for (int i = 0; i < 4; ++i) fa[i] = xb[(size_t)i * SS];
    {
        const float* p = emb + (size_t)dqb * KK + cod_b;
#pragma unroll
        for (int i = 0; i < 8; ++i) fb[i] = p[(size_t)i * KK];
    }
    // convert chunk 0 -> buffer 0
    {
        ushort h[8], l[8];
#pragma unroll
        for (int i = 0; i < 4; ++i) split16(fa[i], h[i], l[i]);
        uint2 w;
        w.x = (uint)h[0] | ((uint)h[1] << 16);
        w.y = (uint)h[2] | ((uint)h[3] << 16);
        *reinterpret_cast<uint2*>(&Ah[0][lat_a * LDA + dqa]) = w;
        w.x = (uint)l[0] | ((uint)l[1] << 16);
        w.y = (uint)l[2] | ((uint)l[3] << 16);
        *reinterpret_cast<uint2*>(&Al[0][lat_a * LDA + dqa]) = w;
#pragma unroll
        for (int i = 0; i < 8; ++i) split16(fb[i], h[i], l[i]);
        uint4 t;
        t.x = (uint)h[0] | ((uint)h[1] << 16);
        t.y = (uint)h[2] | ((uint)h[3] << 16);
        t.z = (uint)h[4] | ((uint)h[5] << 16);
        t.w = (uint)h[6] | ((uint)h[7] << 16);
        *reinterpret_cast<uint4*>(&Bh[0][cod_b * LDA + dqb]) = t;
        t.x = (uint)l[0] | ((uint)l[1] << 16);
        t.y = (uint)l[2] | ((uint)l[3] << 16);
        t.z = (uint)l[4] | ((uint)l[5] << 16);
        t.w = (uint)l[6] | ((uint)l[7] << 16);
        *reinterpret_cast<uint4*>(&Bl[0][cod_b * LDA + dqb]) = t;
    }
    __syncthreads();

    for (int c = 0; c < 128; ++c) {          // 8 kt x 16 dt chunks of K-depth 16
        const int cur = c & 1, nxt = cur ^ 1;
        // ---- prefetch next chunk's globals (in flight during MFMA) ----
        if (c < 127) {
            const int c1 = c + 1;
            const int kt1 = c1 >> 4;
            const int dt1 = (c1 & 15) * 16;
#pragma unroll
            for (int i = 0; i < 4; ++i) fa[i] = xb[(size_t)(dt1 + i) * SS];
            const float* p = emb + (size_t)(dt1 + dqb) * KK + kt1 * NTT + cod_b;
#pragma unroll
            for (int i = 0; i < 8; ++i) fb[i] = p[(size_t)i * KK];
        }
        // ---- fragments from current buffer + 12 MFMA (3 terms x 2x2) ----
        const int fo = colk * LDA + half * 8;
        half8v ah0 = *reinterpret_cast<const half8v*>(&Ah[cur][fo + wm * LDA]);
        half8v ah1 = *reinterpret_cast<const half8v*>(&Ah[cur][fo + (wm + 32) * LDA]);
        half8v al0 = *reinterpret_cast<const half8v*>(&Al[cur][fo + wm * LDA]);
        half8v al1 = *reinterpret_cast<const half8v*>(&Al[cur][fo + (wm + 32) * LDA]);
        half8v bh0 = *reinterpret_cast<const half8v*>(&Bh[cur][fo + wn * LDA]);
        half8v bh1 = *reinterpret_cast<const half8v*>(&Bh[cur][fo + (wn + 32) * LDA]);
        half8v bl0 = *reinterpret_cast<const half8v*>(&Bl[cur][fo + wn * LDA]);
        half8v bl1 = *reinterpret_cast<const half8v*>(&Bl[cur][fo + (wn + 32) * LDA]);

        acc[0][0] = MFMA_F16(ah0, bh0, acc[0][0], 0, 0, 0);
        acc[0][0] = MFMA_F16(ah0, bl0, acc[0][0], 0, 0, 0);
        acc[0][0] = MFMA_F16(al0, bh0, acc[0][0], 0, 0, 0);

        acc[0][1] = MFMA_F16(ah0, bh1, acc[0][1], 0, 0, 0);
        acc[0][1] = MFMA_F16(ah0, bl1, acc[0][1], 0, 0, 0);
        acc[0][1] = MFMA_F16(al0, bh1, acc[0][1], 0, 0, 0);

        acc[1][0] = MFMA_F16(ah1, bh0, acc[1][0], 0, 0, 0);
        acc[1][0] = MFMA_F16(ah1, bl0, acc[1][0], 0, 0, 0);
        acc[1][0] = MFMA_F16(al1, bh0, acc[1][0], 0, 0, 0);

        acc[1][1] = MFMA_F16(ah1, bh1, acc[1][1], 0, 0, 0);
        acc[1][1] = MFMA_F16(ah1, bl1, acc[1][1], 0, 0, 0);
        acc[1][1] = MFMA_F16(al1, bh1, acc[1][1], 0, 0, 0);

        // ---- convert prefetched -> write NEXT buffer (overlaps MFMA) ----
        if (c < 127) {
            ushort h[8], l[8];
#pragma unroll
            for (int i = 0; i < 4; ++i) split16(fa[i], h[i], l[i]);
            uint2 w;
            w.x = (uint)h[0] | ((uint)h[1] << 16);
            w.y = (uint)h[2] | ((uint)h[3] << 16);
            *reinterpret_cast<uint2*>(&Ah[nxt][lat_a * LDA + dqa]) = w;
            w.x = (uint)l[0] | ((uint)l[1] << 16);
            w.y = (uint)l[2] | ((uint)l[3] << 16);
            *reinterpret_cast<uint2*>(&Al[nxt][lat_a * LDA + dqa]) = w;
#pragma unroll
            for (int i = 0; i < 8; ++i) split16(fb[i], h[i], l[i]);
            uint4 t;
            t.x = (uint)h[0] | ((uint)h[1] << 16);
            t.y = (uint)h[2] | ((uint)h[3] << 16);
            t.z = (uint)h[4] | ((uint)h[5] << 16);
            t.w = (uint)h[6] | ((uint)h[7] << 16);
            *reinterpret_cast<uint4*>(&Bh[nxt][cod_b * LDA + dqb]) = t;
            t.x = (uint)l[0] | ((uint)l[1] << 16);
            t.y = (uint)l[2] | ((uint)l[3] << 16);
            t.z = (uint)l[4] | ((uint)l[5] << 16);
            t.w = (uint)l[6] | ((uint)l[7] << 16);
            *reinterpret_cast<uint4*>(&Bl[nxt][cod_b * LDA + dqb]) = t;
        }
        // ---- per-kt epilogue: scores -> running per-lane argmin, reset acc ----
        if ((c & 15) == 15) {
            const int kt = c >> 4;
            const int cd0 = kt * NTT + wn + colk;
            const int cd1 = cd0 + 32;
            const float h0 = hn[cd0];
            const float h1 = hn[cd1];
#pragma unroll
            for (int tm = 0; tm < 2; ++tm) {
#pragma unroll
                for (int r = 0; r < 16; ++r) {
                    float s0 = h0 - acc[tm][0][r];
                    float s1 = h1 - acc[tm][1][r];
                    float v = s0; int cd = cd0;
                    if (s1 < s0) { v = s1; cd = cd1; }   // strict <: smaller code wins ties
                    if (v < bestv[tm][r]) { bestv[tm][r] = v; bestc[tm][r] = cd; }
                    acc[tm][0][r] = 0.f;
                    acc[tm][1][r] = 0.f;
                }
            }
        }
        __syncthreads();   // single barrier per chunk (dbuf)
    }

    // ---- cross-lane argmin: butterfly over the 32 colk lanes ----
#pragma unroll
    for (int tm = 0; tm < 2; ++tm) {
#pragma unroll
        for (int r = 0; r < 16; ++r) {
            float v = bestv[tm][r];
            int cd = bestc[tm][r];
#pragma unroll
            for (int mk = 1; mk < 32; mk <<= 1) {
                float ov = __shfl_xor(v, mk);
                int oc = __shfl_xor(cd, mk);
                if (ov < v || (ov == v && oc < cd)) { v = ov; cd = oc; }
            }
            if (colk == 0) {
                const int row = (r & 3) + 8 * (r >> 2) + 4 * half;  // verified C/D map
                sv[wid >> 1][wm + tm * 32 + row] = v;
                sc[wid >> 1][wm + tm * 32 + row] = cd;
            }
        }
    }
    __syncthreads();
    // ---- combine the 4 n-wave groups ----
    if (tid < MT) {
        float v = sv[0][tid]; int cd = sc[0][tid];
#pragma unroll
        for (int g = 1; g < 4; ++g) {
            float ov = sv[g][tid]; int oc = sc[g][tid];
            if (ov < v || (ov == v && oc < cd)) { v = ov; cd = oc; }
        }
        bc[tid] = cd;
    }
    __syncthreads();
    // ---- fused gather: out[(bq*DD+d)*SS + sb + m] = emb[d*KK + bc[m]] ----
    {
        const int mq = tid & 31;     // float4 group along m
        const int dg = tid >> 5;     // 0..15, 16 d's each
        const int k0 = bc[mq * 4 + 0];
        const int k1 = bc[mq * 4 + 1];
        const int k2 = bc[mq * 4 + 2];
        const int k3 = bc[mq * 4 + 3];
#pragma unroll 4
        for (int dd = 0; dd < 16; ++dd) {
            const int d = dg * 16 + dd;
            const float* er = emb + (size_t)d * KK;
            float4 o = make_float4(er[k0], er[k1], er[k2], er[k3]);
            reinterpret_cast<float4*>(&out[((size_t)bq * DD + d) * SS + sb])[mq] = o;
        }
    }
}

extern "C" void kernel_launch(void* const* d_in, const int* in_sizes, int n_in,
                              void* d_out, int out_size, void* d_ws, size_t ws_size,
                              hipStream_t stream) {
    const float* x = (const float*)d_in[0];     // (32,256,32,32)
    const float* emb = (const float*)d_in[1];   // (256,2048)
    float* out = (float*)d_out;
    float* hn = (float*)d_ws;                   // 2048 f32 = 8 KB (proven safe)

    hipLaunchKernelGGL(hn_kernel, dim3(KK / 256), dim3(256), 0, stream, emb, hn);
    hipLaunchKernelGGL(vq_fused, dim3(NN / MT), dim3(512), 0, stream,
                       x, emb, hn, out);
}